// Round 1
// baseline (2541.028 us; speedup 1.0000x reference)
//
#include <hip/hip_runtime.h>

// ---------------------------------------------------------------------------
// RnnFamily_386547057206: 2-layer GRU memory update + MLP decoder (TGN-style)
//   x = node_embs[ids]; h = memory[ids]
//   h0' = GRU(x, h0; W0,U0,b0); h1' = GRU(h0', h1; W1,U1,b1)
//   new_memory = memory with rows[ids] <- [h0', h1']
//   out = relu(h1'@Wd1+bd1)@Wd2 + bd2
// Strategy: bf16 MFMA (16x16x32) for all GEMMs, fp32 epilogues.
//   - prep: weights -> bf16, transposed [N][K] (B-fragment friendly), in ws
//   - flags: mark updated rows; copy kernel moves only untouched rows
//   - fused kernel: M_TILE=64 rows/block, 4 waves split N (16 cols each)
// ---------------------------------------------------------------------------

typedef __attribute__((ext_vector_type(8))) short short8;   // 8 x bf16 (4 VGPR)
typedef __attribute__((ext_vector_type(4))) float f32x4;    // MFMA C/D

#define MFMA(a, b, c) __builtin_amdgcn_mfma_f32_16x16x32_bf16((a), (b), (c), 0, 0, 0)

#define NROWS 500000
#define BATCH 131072
#define MT    64      // rows per block
#define LDSP  264     // LDS row stride in shorts (256 + 8 pad -> 2-way-max bank alias)

__device__ __forceinline__ short f2bf(float f) {
    unsigned u = __float_as_uint(f);
    u += 0x7fffu + ((u >> 16) & 1u);     // round-to-nearest-even
    return (short)(u >> 16);
}
__device__ __forceinline__ float bf2f(short s) {
    return __uint_as_float(((unsigned)(unsigned short)s) << 16);
}
__device__ __forceinline__ float sigmoidf_(float x) {
    return __builtin_amdgcn_rcpf(1.f + __expf(-x));
}
__device__ __forceinline__ float tanhf_(float x) {
    float e = __expf(2.f * x);
    return 1.f - 2.f * __builtin_amdgcn_rcpf(e + 1.f);
}

// --- weight prep: bf16 + transpose ----------------------------------------
// wc[n*512 + k] = (k<256 ? W[k][n] : U[k-256][n]) for n in [0,768)
// wd1t[n*256+k] = Wd1[k][n] (n<256); wd2t[n*256+k] = Wd2[k][n] (n<64)
__global__ void prep_weights(const float* __restrict__ W0, const float* __restrict__ U0,
                             const float* __restrict__ W1, const float* __restrict__ U1,
                             const float* __restrict__ Wd1, const float* __restrict__ Wd2,
                             short* __restrict__ wc0, short* __restrict__ wc1,
                             short* __restrict__ wd1t, short* __restrict__ wd2t) {
    int t = blockIdx.x * 256 + threadIdx.x;
    if (t < 393216) {
        int k = t & 511, n = t >> 9;
        float v = (k < 256) ? W0[k * 768 + n] : U0[(k - 256) * 768 + n];
        wc0[t] = f2bf(v);
    } else if (t < 786432) {
        int tt = t - 393216;
        int k = tt & 511, n = tt >> 9;
        float v = (k < 256) ? W1[k * 768 + n] : U1[(k - 256) * 768 + n];
        wc1[tt] = f2bf(v);
    } else if (t < 851968) {
        int tt = t - 786432;
        int k = tt & 255, n = tt >> 8;
        wd1t[tt] = f2bf(Wd1[k * 256 + n]);
    } else if (t < 868352) {
        int tt = t - 851968;
        int k = tt & 255, n = tt >> 8;
        wd2t[tt] = f2bf(Wd2[k * 64 + n]);
    }
}

__global__ void set_flags(const int* __restrict__ ids, unsigned char* __restrict__ flags) {
    int t = blockIdx.x * 256 + threadIdx.x;
    flags[ids[t]] = 1;
}

// copy untouched rows: 4 rows / 256-thread block, 2 float4 per lane per row
__global__ void copy_rows(const float4* __restrict__ mem4,
                          const unsigned char* __restrict__ flags,
                          float4* __restrict__ out4) {
    int row  = blockIdx.x * 4 + (threadIdx.x >> 6);
    int lane = threadIdx.x & 63;
    if (flags[row]) return;                     // uniform per 64-lane group
    const float4* s = mem4 + (size_t)row * 128;
    float4*       d = out4 + (size_t)row * 128;
    d[lane * 2]     = s[lane * 2];
    d[lane * 2 + 1] = s[lane * 2 + 1];
}

// --- one GRU layer ---------------------------------------------------------
// Xs holds layer input (k 0..255), Hs holds h_prev (k 0..255), both bf16.
// Wc is [768][512]: rows 0..255 of k = W, 256..511 = U.
// z,r gates: fused K=512 accumulation. h gate: W-part and U-part separate
// (r multiplies only the U*h term).
// Ends: barrier, h_new -> Xs, optional Hs reload (next layer's h), barrier.
__device__ __forceinline__ void gru_layer(
    short* Xs, short* Hs, const int* ids_s,
    const short* __restrict__ Wc, const float* __restrict__ bias,
    float* __restrict__ outm, int layer,
    const float* __restrict__ gather_src, int tid) {
    const int wid = tid >> 6, lane = tid & 63;
    const int l16 = lane & 15, q = lane >> 4;
    unsigned hk[4][4][2];
    const f32x4 z4 = {0.f, 0.f, 0.f, 0.f};

    #pragma unroll
    for (int n0i = 0; n0i < 4; ++n0i) {
        const int nw = n0i * 64 + wid * 16;
        f32x4 accz[4], accr[4], acchx[4], acchh[4];
        #pragma unroll
        for (int mi = 0; mi < 4; ++mi) { accz[mi] = z4; accr[mi] = z4; acchx[mi] = z4; acchh[mi] = z4; }
        const short* pz = Wc + (size_t)(nw + l16) * 512 + q * 8;
        const short* pr = pz + 256 * 512;
        const short* ph = pz + 512 * 512;
        #pragma unroll
        for (int k0 = 0; k0 < 256; k0 += 32) {              // W half (A = Xs)
            short8 bz = *(const short8*)(pz + k0);
            short8 br = *(const short8*)(pr + k0);
            short8 bh = *(const short8*)(ph + k0);
            #pragma unroll
            for (int mi = 0; mi < 4; ++mi) {
                short8 a = *(const short8*)(Xs + (mi * 16 + l16) * LDSP + k0 + q * 8);
                accz[mi]  = MFMA(a, bz, accz[mi]);
                accr[mi]  = MFMA(a, br, accr[mi]);
                acchx[mi] = MFMA(a, bh, acchx[mi]);
            }
        }
        #pragma unroll
        for (int k0 = 0; k0 < 256; k0 += 32) {              // U half (A = Hs)
            short8 bz = *(const short8*)(pz + 256 + k0);
            short8 br = *(const short8*)(pr + 256 + k0);
            short8 bh = *(const short8*)(ph + 256 + k0);
            #pragma unroll
            for (int mi = 0; mi < 4; ++mi) {
                short8 a = *(const short8*)(Hs + (mi * 16 + l16) * LDSP + k0 + q * 8);
                accz[mi]  = MFMA(a, bz, accz[mi]);
                accr[mi]  = MFMA(a, br, accr[mi]);
                acchh[mi] = MFMA(a, bh, acchh[mi]);
            }
        }
        const int col = nw + l16;
        const float bz_ = bias[col], br_ = bias[256 + col], bh_ = bias[512 + col];
        #pragma unroll
        for (int mi = 0; mi < 4; ++mi) {
            #pragma unroll
            for (int r = 0; r < 4; ++r) {
                int row = mi * 16 + q * 4 + r;
                float z  = sigmoidf_(accz[mi][r] + bz_);
                float rr = sigmoidf_(accr[mi][r] + br_);
                float hh = tanhf_(acchx[mi][r] + bh_ + rr * acchh[mi][r]);
                float hold = bf2f(Hs[row * LDSP + col]);
                float hnew = z * hold + (1.f - z) * hh;
                outm[(size_t)ids_s[row] * 512 + layer * 256 + col] = hnew;
                unsigned v = (unsigned)(unsigned short)f2bf(hnew);
                if (r & 1) hk[n0i][mi][r >> 1] |= v << 16;
                else       hk[n0i][mi][r >> 1]  = v;
            }
        }
    }
    __syncthreads();                      // everyone done reading Xs/Hs
    #pragma unroll
    for (int n0i = 0; n0i < 4; ++n0i) {   // h_new -> Xs (next layer's input)
        const int col = n0i * 64 + wid * 16 + l16;
        #pragma unroll
        for (int mi = 0; mi < 4; ++mi) {
            #pragma unroll
            for (int r = 0; r < 4; ++r) {
                int row = mi * 16 + q * 4 + r;
                Xs[row * LDSP + col] = (short)(hk[n0i][mi][r >> 1] >> ((r & 1) * 16));
            }
        }
    }
    if (gather_src) {                     // Hs <- memory[ids][1][:] for layer 1
        const int c4 = tid & 63, r0 = tid >> 6;
        #pragma unroll
        for (int p = 0; p < 16; ++p) {
            int row = p * 4 + r0;
            size_t id = (size_t)ids_s[row];
            float4 vh = *(const float4*)(gather_src + id * 512 + 256 + c4 * 4);
            short4 sh = make_short4(f2bf(vh.x), f2bf(vh.y), f2bf(vh.z), f2bf(vh.w));
            *(short4*)(&Hs[row * LDSP + c4 * 4]) = sh;
        }
    }
    __syncthreads();
}

__global__ __launch_bounds__(256) void fused_kernel(
    const float* __restrict__ node_embs, const float* __restrict__ memory,
    const int* __restrict__ ids,
    const short* __restrict__ Wc0, const short* __restrict__ Wc1,
    const short* __restrict__ Wd1t, const short* __restrict__ Wd2t,
    const float* __restrict__ b0, const float* __restrict__ b1,
    const float* __restrict__ bd1, const float* __restrict__ bd2,
    float* __restrict__ out0, float* __restrict__ outm) {
    __shared__ __align__(16) short Xs[MT * LDSP];
    __shared__ __align__(16) short Hs[MT * LDSP];
    __shared__ int ids_s[MT];

    const int tid = threadIdx.x, blk = blockIdx.x;
    const int wid = tid >> 6, lane = tid & 63;
    const int l16 = lane & 15, q = lane >> 4;
    const f32x4 z4 = {0.f, 0.f, 0.f, 0.f};

    if (tid < MT) ids_s[tid] = ids[blk * MT + tid];
    __syncthreads();

    {   // gather x -> Xs, h0 -> Hs (fp32 -> bf16)
        const int c4 = tid & 63, r0 = tid >> 6;
        #pragma unroll
        for (int p = 0; p < 16; ++p) {
            int row = p * 4 + r0;
            size_t id = (size_t)ids_s[row];
            float4 vx = *(const float4*)(node_embs + id * 256 + c4 * 4);
            float4 vh = *(const float4*)(memory + id * 512 + c4 * 4);
            short4 sx = make_short4(f2bf(vx.x), f2bf(vx.y), f2bf(vx.z), f2bf(vx.w));
            short4 sh = make_short4(f2bf(vh.x), f2bf(vh.y), f2bf(vh.z), f2bf(vh.w));
            *(short4*)(&Xs[row * LDSP + c4 * 4]) = sx;
            *(short4*)(&Hs[row * LDSP + c4 * 4]) = sh;
        }
    }
    __syncthreads();

    gru_layer(Xs, Hs, ids_s, Wc0, b0, outm, 0, memory, tid);   // also reloads Hs <- h1
    gru_layer(Xs, Hs, ids_s, Wc1, b1, outm, 1, nullptr, tid);  // Xs now holds h1_new

    // decoder GEMM1: T = relu(h1' @ Wd1 + bd1) -> Hs
    {
        unsigned tk[4][4][2];
        #pragma unroll
        for (int n0i = 0; n0i < 4; ++n0i) {
            const int nw = n0i * 64 + wid * 16;
            f32x4 acc[4];
            #pragma unroll
            for (int mi = 0; mi < 4; ++mi) acc[mi] = z4;
            const short* pw = Wd1t + (size_t)(nw + l16) * 256 + q * 8;
            #pragma unroll
            for (int k0 = 0; k0 < 256; k0 += 32) {
                short8 b = *(const short8*)(pw + k0);
                #pragma unroll
                for (int mi = 0; mi < 4; ++mi) {
                    short8 a = *(const short8*)(Xs + (mi * 16 + l16) * LDSP + k0 + q * 8);
                    acc[mi] = MFMA(a, b, acc[mi]);
                }
            }
            const float bb = bd1[nw + l16];
            #pragma unroll
            for (int mi = 0; mi < 4; ++mi) {
                #pragma unroll
                for (int r = 0; r < 4; ++r) {
                    float t = acc[mi][r] + bb;
                    t = t > 0.f ? t : 0.f;
                    unsigned v = (unsigned)(unsigned short)f2bf(t);
                    if (r & 1) tk[n0i][mi][r >> 1] |= v << 16;
                    else       tk[n0i][mi][r >> 1]  = v;
                }
            }
        }
        __syncthreads();
        #pragma unroll
        for (int n0i = 0; n0i < 4; ++n0i) {
            const int col = n0i * 64 + wid * 16 + l16;
            #pragma unroll
            for (int mi = 0; mi < 4; ++mi) {
                #pragma unroll
                for (int r = 0; r < 4; ++r) {
                    int row = mi * 16 + q * 4 + r;
                    Hs[row * LDSP + col] = (short)(tk[n0i][mi][r >> 1] >> ((r & 1) * 16));
                }
            }
        }
        __syncthreads();
    }

    // decoder GEMM2: out = T @ Wd2 + bd2   (N=64: wave wid covers cols wid*16..)
    {
        const int nw = wid * 16;
        f32x4 acc[4];
        #pragma unroll
        for (int mi = 0; mi < 4; ++mi) acc[mi] = z4;
        const short* pw = Wd2t + (size_t)(nw + l16) * 256 + q * 8;
        #pragma unroll
        for (int k0 = 0; k0 < 256; k0 += 32) {
            short8 b = *(const short8*)(pw + k0);
            #pragma unroll
            for (int mi = 0; mi < 4; ++mi) {
                short8 a = *(const short8*)(Hs + (mi * 16 + l16) * LDSP + k0 + q * 8);
                acc[mi] = MFMA(a, b, acc[mi]);
            }
        }
        const float bb = bd2[nw + l16];
        #pragma unroll
        for (int mi = 0; mi < 4; ++mi) {
            #pragma unroll
            for (int r = 0; r < 4; ++r) {
                int row = mi * 16 + q * 4 + r;
                out0[(size_t)(blk * MT + row) * 64 + nw + l16] = acc[mi][r] + bb;
            }
        }
    }
}

extern "C" void kernel_launch(void* const* d_in, const int* in_sizes, int n_in,
                              void* d_out, int out_size, void* d_ws, size_t ws_size,
                              hipStream_t stream) {
    const float* node_embs = (const float*)d_in[0];
    const float* memory    = (const float*)d_in[1];
    const float* W0  = (const float*)d_in[2];
    const float* U0  = (const float*)d_in[3];
    const float* b0  = (const float*)d_in[4];
    const float* W1  = (const float*)d_in[5];
    const float* U1  = (const float*)d_in[6];
    const float* b1  = (const float*)d_in[7];
    const float* Wd1 = (const float*)d_in[8];
    const float* bd1 = (const float*)d_in[9];
    const float* Wd2 = (const float*)d_in[10];
    const float* bd2 = (const float*)d_in[11];
    const int*   ids = (const int*)d_in[12];

    float* out0 = (float*)d_out;
    float* outm = out0 + (size_t)BATCH * 64;   // new_memory region

    // ws layout: [0,500000) flags | 512KB-aligned bf16 weights (~1.7 MB)
    unsigned char* flags = (unsigned char*)d_ws;
    short* wc0  = (short*)((char*)d_ws + 524288);
    short* wc1  = wc0 + 768 * 512;
    short* wd1t = wc1 + 768 * 512;
    short* wd2t = wd1t + 256 * 256;

    hipMemsetAsync(flags, 0, NROWS, stream);
    prep_weights<<<3392, 256, 0, stream>>>(W0, U0, W1, U1, Wd1, Wd2, wc0, wc1, wd1t, wd2t);
    set_flags<<<BATCH / 256, 256, 0, stream>>>(ids, flags);
    copy_rows<<<NROWS / 4, 256, 0, stream>>>((const float4*)memory, flags, (float4*)outm);
    fused_kernel<<<BATCH / MT, 256, 0, stream>>>(node_embs, memory, ids, wc0, wc1,
                                                 wd1t, wd2t, b0, b1, bd1, bd2, out0, outm);
}